// Round 6
// baseline (374.002 us; speedup 1.0000x reference)
//
#include <hip/hip_runtime.h>

typedef __bf16 bf16x8 __attribute__((ext_vector_type(8)));
typedef float f32x4 __attribute__((ext_vector_type(4)));

__device__ __forceinline__ unsigned short f2bf(float f) {
    union { float f; unsigned u; } v; v.f = f;
    unsigned r = v.u + 0x7FFFu + ((v.u >> 16) & 1u);   // round-to-nearest-even
    return (unsigned short)(r >> 16);
}

// ---------------------------------------------------------------------------
// prep mega-kernel: ALL preprocessing in one dispatch.  (unchanged from R4/R5)
// ---------------------------------------------------------------------------
__global__ __launch_bounds__(256) void prep_kernel(
    const float4* __restrict__ inputs4, uint2* __restrict__ InB16,
    float4* __restrict__ out4,
    const float* __restrict__ W0, const float* __restrict__ W1,
    unsigned short* __restrict__ D0, unsigned short* __restrict__ D1,
    const int* __restrict__ mask,
    int* __restrict__ cnt, int* __restrict__ padded,
    const float* __restrict__ memory,
    unsigned short* __restrict__ MemG, unsigned short* __restrict__ MemGT)
{
    __shared__ float tile[32][33];
    __shared__ float tileG[32][132];
    __shared__ int wsum[4];
    __shared__ int kidx32[32];
    const int bid = blockIdx.x;
    const int t = threadIdx.x;

    if (bid < 1024) {
        // ---- gather (with local mask scan), deep-ILP version ----
        const int b = bid >> 5;          // batch
        const int jt = bid & 31;         // j-tile (32 rows)
        const int j0 = jt * 32;
        const int* m = mask + b * 1024;
        int v[4]; int s = 0;
#pragma unroll
        for (int e = 0; e < 4; e++) { v[e] = (m[t * 4 + e] != 0) ? 1 : 0; s += v[e]; }
        const int lane = t & 63, wv = t >> 6;
        int x = s;
#pragma unroll
        for (int off = 1; off < 64; off <<= 1) {
            int y = __shfl_up(x, off, 64);
            if (lane >= off) x += y;
        }
        if (lane == 63) wsum[wv] = x;
        __syncthreads();
        int base = 0;
        for (int w = 0; w < wv; w++) base += wsum[w];
        const int nb = wsum[0] + wsum[1] + wsum[2] + wsum[3];
        const int pb = (nb + 127) & ~127;
        if (j0 >= pb) return;            // block-uniform
        int pos = base + x - s;          // exclusive prefix
#pragma unroll
        for (int e = 0; e < 4; e++)
            if (v[e]) {
                int p = pos++;
                if (p >= j0 && p < j0 + 32) kidx32[p - j0] = t * 4 + e;
            }
        __syncthreads();

        const float4* src4 = (const float4*)(memory + (size_t)b * 1024 * 512);
        const int jj = t >> 3;           // 0..31 (row within tile)
        const int cq = t & 7;            // 0..7  (16-float column chunk)
        const bool live = (j0 + jj) < nb;
        const int krow = live ? kidx32[jj] : 0;

        float4 vv[4][4];
        if (live) {
            const float4* rp = src4 + (size_t)krow * 128 + cq * 4;
#pragma unroll
            for (int c = 0; c < 4; c++)
#pragma unroll
                for (int i = 0; i < 4; i++) vv[c][i] = rp[c * 32 + i];
        } else {
#pragma unroll
            for (int c = 0; c < 4; c++)
#pragma unroll
                for (int i = 0; i < 4; i++) vv[c][i] = float4{0.f, 0.f, 0.f, 0.f};
        }

        unsigned short* mg = MemG + (size_t)b * 1024 * 512 + (size_t)(j0 + jj) * 512;
#pragma unroll
        for (int c = 0; c < 4; c++) {
            union { unsigned short u[16]; uint4 q[2]; } pk;
#pragma unroll
            for (int i = 0; i < 4; i++) {
                pk.u[i * 4 + 0] = f2bf(vv[c][i].x); pk.u[i * 4 + 1] = f2bf(vv[c][i].y);
                pk.u[i * 4 + 2] = f2bf(vv[c][i].z); pk.u[i * 4 + 3] = f2bf(vv[c][i].w);
            }
            *(uint4*)&mg[c * 128 + cq * 16] = pk.q[0];
            *(uint4*)&mg[c * 128 + cq * 16 + 8] = pk.q[1];
        }

        const int dd = t >> 1;           // 0..127 (d within chunk)
        const int jh = (t & 1) * 16;     // j half
        unsigned short* gtb = MemGT + (size_t)b * 512 * 1024 + j0 + jh;
#pragma unroll
        for (int c = 0; c < 4; c++) {
#pragma unroll
            for (int i = 0; i < 4; i++)
                *(float4*)&tileG[jj][cq * 16 + i * 4] = vv[c][i];
            __syncthreads();
            union { unsigned short u[16]; uint4 q[2]; } pt;
#pragma unroll
            for (int k = 0; k < 16; k++) pt.u[k] = f2bf(tileG[jh + k][dd]);
            unsigned short* gt = gtb + (size_t)(c * 128 + dd) * 1024;
            *(uint4*)&gt[0] = pt.q[0];
            *(uint4*)&gt[8] = pt.q[1];
            __syncthreads();
        }
    } else if (bid < 1056) {
        // ---- mask scan -> cnt/padded ----
        const int b = bid - 1024;
        const int* m = mask + b * 1024;
        int s = 0;
#pragma unroll
        for (int e = 0; e < 4; e++) s += (m[t * 4 + e] != 0) ? 1 : 0;
        const int lane = t & 63, wv = t >> 6;
        int x = s;
#pragma unroll
        for (int off = 1; off < 64; off <<= 1) {
            int y = __shfl_up(x, off, 64);
            if (lane >= off) x += y;
        }
        if (lane == 63) wsum[wv] = x;
        __syncthreads();
        if (t == 255) {
            int total = wsum[0] + wsum[1] + wsum[2] + wsum[3];
            cnt[b] = total;
            padded[b] = (total + 127) & ~127;
        }
    } else if (bid < 1568) {
        // ---- weight transpose ----
        const int tb = bid - 1056;
        const float* src = (tb >> 8) ? W1 : W0;
        unsigned short* dst = (tb >> 8) ? D1 : D0;
        const int rem = tb & 255;
        const int s0 = (rem & 15) * 32, d0 = (rem >> 4) * 32;
        const int tr = t >> 5, tc = t & 31;
#pragma unroll
        for (int i = 0; i < 4; i++)
            tile[tr + i * 8][tc] = src[(size_t)(s0 + tr + i * 8) * 512 + d0 + tc];
        __syncthreads();
#pragma unroll
        for (int i = 0; i < 4; i++)
            dst[(size_t)(d0 + tr + i * 8) * 512 + s0 + tc] = f2bf(tile[tc][tr + i * 8]);
    } else {
        // ---- fuse_inputs ----
        const int i = (bid - 1568) * 256 + t;   // 4194304 float4s total
        const int bq = i >> 7;
        const int d  = i & 127;
        float4 v = inputs4[i];
        out4[(size_t)bq * 256 + 128 + d] = v;
        union { unsigned short u[4]; uint2 p; } pk;
        pk.u[0] = f2bf(v.x); pk.u[1] = f2bf(v.y);
        pk.u[2] = f2bf(v.z); pk.u[3] = f2bf(v.w);
        InB16[i] = pk.p;
    }
}

// ---------------------------------------------------------------------------
// 128x128-tile, 4-wave, BK=64, 2-phase bf16 GEMM core (R5, verified) —
// used only for the projections now (CMODE 0).
// ---------------------------------------------------------------------------
__device__ __forceinline__ void gemm_core0(
    unsigned char* lds,
    const unsigned short* __restrict__ Ab, const unsigned short* __restrict__ Bb,
    unsigned short* __restrict__ C,
    int rowA, int rowB, int Kz, int lda, int ldb, int ldc)
{
    const int nt = Kz >> 6;

    const int t = threadIdx.x;              // 0..255
    const int w = t >> 6;
    const int lane = t & 63;
    const int wm = w >> 1;
    const int wn = w & 1;
    const int l15 = lane & 15;
    const int sx = (((lane >> 4) ^ ((l15 >> 1) & 3)) << 4);

    const int r0 = t >> 2;
    const int sl = (t & 3) ^ ((t >> 3) & 3);
    const unsigned short* aS0 = Ab + (size_t)(rowA + r0) * lda + sl * 8;
    const unsigned short* aS1 = aS0 + (size_t)64 * lda;
    const unsigned short* bS0 = Bb + (size_t)(rowB + r0) * ldb + sl * 8;
    const unsigned short* bS1 = bS0 + (size_t)64 * ldb;

    const int wofs = w * 1024;
    const int aRd = (wm * 64 + l15) * 64 + sx;
    const int bRd = 16384 + (wn * 64 + l15) * 64 + sx;

    f32x4 acc[4][4];
#pragma unroll
    for (int i = 0; i < 4; i++)
#pragma unroll
        for (int j = 0; j < 4; j++) acc[i][j] = f32x4{0.f, 0.f, 0.f, 0.f};

#define GLL(SRC, DOFS) __builtin_amdgcn_global_load_lds(                        \
        (const __attribute__((address_space(1))) void*)(SRC),                   \
        (__attribute__((address_space(3))) void*)&lds[DOFS], 16, 0, 0)
#define STAGEA(BUF, KH, KEL) do {                                               \
        GLL(aS0 + (KEL), (BUF) * 32768 + (KH) * 8192 + wofs);                   \
        GLL(aS1 + (KEL), (BUF) * 32768 + (KH) * 8192 + wofs + 4096); } while (0)
#define STAGEB(BUF, KH, KEL) do {                                               \
        GLL(bS0 + (KEL), (BUF) * 32768 + 16384 + (KH) * 8192 + wofs);           \
        GLL(bS1 + (KEL), (BUF) * 32768 + 16384 + (KH) * 8192 + wofs + 4096); } while (0)

    STAGEA(0, 0, 0); STAGEB(0, 0, 0); STAGEA(0, 1, 32); STAGEB(0, 1, 32);
    asm volatile("s_waitcnt vmcnt(4)" ::: "memory");
    __builtin_amdgcn_s_barrier();

    for (int tt = 0; tt < nt; ++tt) {
        const int cur = (tt & 1) * 32768;
        const int nxt = (tt & 1) ^ 1;
        const bool pf = (tt + 1) < nt;
        const int kn = (tt + 1) * 64;
        bf16x8 af[4], bfr[4];

#pragma unroll
        for (int i = 0; i < 4; i++) af[i]  = *(const bf16x8*)&lds[cur + aRd + i * 1024];
#pragma unroll
        for (int j = 0; j < 4; j++) bfr[j] = *(const bf16x8*)&lds[cur + bRd + j * 1024];
        if (pf) { STAGEA(nxt, 0, kn); STAGEB(nxt, 0, kn); }
        __builtin_amdgcn_s_barrier();
        asm volatile("s_waitcnt lgkmcnt(0)" ::: "memory");
        __builtin_amdgcn_sched_barrier(0);
        __builtin_amdgcn_s_setprio(1);
#pragma unroll
        for (int i = 0; i < 4; i++)
#pragma unroll
            for (int j = 0; j < 4; j++)
                acc[i][j] = __builtin_amdgcn_mfma_f32_16x16x32_bf16(af[i], bfr[j], acc[i][j], 0, 0, 0);
        __builtin_amdgcn_s_setprio(0);
        if (pf) { asm volatile("s_waitcnt vmcnt(4)" ::: "memory"); }
        else    { asm volatile("s_waitcnt vmcnt(0)" ::: "memory"); }
        __builtin_amdgcn_s_barrier();

#pragma unroll
        for (int i = 0; i < 4; i++) af[i]  = *(const bf16x8*)&lds[cur + 8192 + aRd + i * 1024];
#pragma unroll
        for (int j = 0; j < 4; j++) bfr[j] = *(const bf16x8*)&lds[cur + 8192 + bRd + j * 1024];
        if (pf) { STAGEA(nxt, 1, kn + 32); STAGEB(nxt, 1, kn + 32); }
        __builtin_amdgcn_s_barrier();
        asm volatile("s_waitcnt lgkmcnt(0)" ::: "memory");
        __builtin_amdgcn_sched_barrier(0);
        __builtin_amdgcn_s_setprio(1);
#pragma unroll
        for (int i = 0; i < 4; i++)
#pragma unroll
            for (int j = 0; j < 4; j++)
                acc[i][j] = __builtin_amdgcn_mfma_f32_16x16x32_bf16(af[i], bfr[j], acc[i][j], 0, 0, 0);
        __builtin_amdgcn_s_setprio(0);
        if (pf) { asm volatile("s_waitcnt vmcnt(4)" ::: "memory"); }
        __builtin_amdgcn_s_barrier();
    }

#undef GLL
#undef STAGEA
#undef STAGEB

    const int orow = (lane >> 4) * 4;
    const int ocol = l15;
#pragma unroll
    for (int mf = 0; mf < 4; mf++)
#pragma unroll
        for (int nf = 0; nf < 4; nf++) {
            const int col = rowB + wn * 64 + nf * 16 + ocol;
#pragma unroll
            for (int r = 0; r < 4; r++) {
                const int rw = rowA + wm * 64 + mf * 16 + orow + r;
                C[(size_t)rw * ldc + col] = f2bf(fmaxf(acc[mf][nf][r], 0.f));
            }
        }
}

__global__ __launch_bounds__(256, 2) void gemm_proj_kernel(
    const unsigned short* __restrict__ InB16, const unsigned short* __restrict__ WtIn,
    unsigned short* __restrict__ Xq,
    const unsigned short* __restrict__ MemG, const unsigned short* __restrict__ WtMem,
    unsigned short* __restrict__ Xm, const int* __restrict__ padded)
{
    __shared__ __align__(16) unsigned char lds[65536];
    const int id = blockIdx.x;
    const int xcd = id & 7, u8 = id >> 3;
    const int y = xcd + 8 * (u8 >> 2);
    const int x = u8 & 3;
    const int rowB = x * 128;
    const unsigned short* A;
    const unsigned short* Bt;
    unsigned short* C;
    int rowA;
    if (y < 256) {
        A = InB16; Bt = WtIn; C = Xq; rowA = y * 128;
    } else {
        const int idx = y - 256;
        const int z = idx >> 3;
        rowA = (idx & 7) * 128;
        if (rowA >= padded[z]) return;
        A = MemG + (size_t)z * 524288;
        Bt = WtMem;
        C = Xm + (size_t)z * 524288;
    }
    gemm_core0(lds, A, Bt, C, rowA, rowB, 512, 512, 512, 512);
}

// ---------------------------------------------------------------------------
// Fused P+context flash kernel.
//   Block: batch z, q-tile of 64 rows, 256 threads (4 waves), 2 blocks/CU.
//   Per k-tile (64 rows of active memory):
//     S^T = Xm_kt @ Xq^T  (C cols = q = lane&15 -> P lane-local per q)
//     P = masked exp;  rowsum accumulated in-register.
//     P -> 8 KiB swizzled LDS; PV: ctx += P @ MemGT^T (B direct from global/L2)
//   Epilogue: ctx / rowsum -> out[..., 0:512] fp32.   No P buffer, no atomics.
// LDS: XmBuf[2][64][128] @0/16384 | XqBuf[2][64][128] @32768/49152
//      P[64][64] @65536 | rs[64] @73728     (73984 B total)
// ---------------------------------------------------------------------------
__global__ __launch_bounds__(256, 2) void fused_attn_kernel(
    const unsigned short* __restrict__ Xq, const unsigned short* __restrict__ Xm,
    const unsigned short* __restrict__ MemGT, float* __restrict__ out,
    const int* __restrict__ cnt, const int* __restrict__ padded, float scale)
{
    __shared__ __align__(16) unsigned char lds[73984];
    const int id = blockIdx.x;
    const int xcd = id & 7, u = id >> 3;
    const int z = xcd + 8 * (u >> 4);        // 4 batches per XCD
    const int q0 = (u & 15) * 64;
    const int cz = cnt[z];
    const int nkt = padded[z] >> 6;

    const int t = threadIdx.x;
    const int w = t >> 6;                    // wave 0..3
    const int lane = t & 63;
    const int g = lane >> 4;                 // 0..3
    const int l15 = lane & 15;

    const unsigned short* XqZ = Xq + (size_t)z * 524288 + (size_t)q0 * 512;
    const unsigned short* XmZ = Xm + (size_t)z * 524288;
    const unsigned short* GTZ = MemGT + (size_t)z * 524288;
    float* outZ = out + (size_t)z * 1048576 + (size_t)q0 * 1024;

    // staging geometry: thread covers rows (i*16 + t>>4), logical slot (t&15)^(t>>4)
    const int srow = t >> 4;
    const int sslot = (t & 15) ^ srow;

    f32x4 acc[4][8];                         // [qt][dt] : 64q x 512d (wave d-slice)
#pragma unroll
    for (int i = 0; i < 4; i++)
#pragma unroll
        for (int j = 0; j < 8; j++) acc[i][j] = f32x4{0.f, 0.f, 0.f, 0.f};
    f32x4 s[4];                              // S^T acc: 64k x 16q (wave q-cols)
#pragma unroll
    for (int i = 0; i < 4; i++) s[i] = f32x4{0.f, 0.f, 0.f, 0.f};
    float rsum = 0.f;

#define GLL(SRC, DOFS) __builtin_amdgcn_global_load_lds(                        \
        (const __attribute__((address_space(1))) void*)(SRC),                   \
        (__attribute__((address_space(3))) void*)&lds[DOFS], 16, 0, 0)
    // stage one 128-elem K-chunk of Xm(kt) and Xq into buffer BUF (8 gll/thread)
#define STAGE_XMQ(BUF, KT, KK) do {                                             \
        _Pragma("unroll")                                                       \
        for (int i_ = 0; i_ < 4; i_++) {                                        \
            GLL(XmZ + (size_t)((KT) * 64 + i_ * 16 + srow) * 512 + (KK) * 128 + sslot * 8, \
                (BUF) * 16384 + i_ * 4096 + t * 16);                            \
            GLL(XqZ + (size_t)(i_ * 16 + srow) * 512 + (KK) * 128 + sslot * 8,  \
                32768 + (BUF) * 16384 + i_ * 4096 + t * 16);                    \
        } } while (0)

    if (nkt > 0) STAGE_XMQ(0, 0, 0);

    for (int kt = 0; kt < nkt; ++kt) {
        // ================= S^T phase: s[t4] += Xm_frag x Xq_frag ============
#pragma unroll 1
        for (int kk = 0; kk < 4; ++kk) {
            const int bcur = (kk & 1) * 16384;
            if (kk < 3) {
                STAGE_XMQ((kk + 1) & 1, kt, kk + 1);
                asm volatile("s_waitcnt vmcnt(8)" ::: "memory");
            } else {
                asm volatile("s_waitcnt vmcnt(0)" ::: "memory");
            }
            __builtin_amdgcn_s_barrier();
            __builtin_amdgcn_s_setprio(1);
#pragma unroll
            for (int c = 0; c < 4; c++) {
                const int so = (((g + 4 * c) ^ l15) << 4);
                bf16x8 bq = *(const bf16x8*)&lds[32768 + bcur + (w * 16 + l15) * 256 + so];
#pragma unroll
                for (int i = 0; i < 4; i++) {
                    bf16x8 am = *(const bf16x8*)&lds[bcur + (i * 16 + l15) * 256 + so];
                    s[i] = __builtin_amdgcn_mfma_f32_16x16x32_bf16(am, bq, s[i], 0, 0, 0);
                }
            }
            __builtin_amdgcn_s_setprio(0);
            __builtin_amdgcn_s_barrier();
        }

        // ================= P extract: exp, mask, rowsum, LDS write ==========
        {
            const int q = w * 16 + l15;
            const int kbase = kt * 64 + g * 4;
#pragma unroll
            for (int t4 = 0; t4 < 4; t4++) {
                float p0 = (kbase + t4 * 16 + 0 < cz) ? __expf(s[t4][0] * scale) : 0.f;
                float p1 = (kbase + t4 * 16 + 1 < cz) ? __expf(s[t4][1] * scale) : 0.f;
                float p2 = (kbase + t4 * 16 + 2 < cz) ? __expf(s[t4][2] * scale) : 0.f;
                float p3 = (kbase + t4 * 16 + 3 < cz) ? __expf(s[t4][3] * scale) : 0.f;
                rsum += (p0 + p1) + (p2 + p3);
                unsigned lo = (unsigned)f2bf(p0) | ((unsigned)f2bf(p1) << 16);
                unsigned hi = (unsigned)f2bf(p2) | ((unsigned)f2bf(p3) << 16);
                const int base = 65536 + q * 128 +
                    (((2 * t4 + (g >> 1)) ^ (q & 7)) << 4) + ((g & 1) << 3);
                *(unsigned*)&lds[base]     = lo;
                *(unsigned*)&lds[base + 4] = hi;
                s[t4] = f32x4{0.f, 0.f, 0.f, 0.f};
            }
        }
        __syncthreads();    // P visible to all waves (drains lgkm)

        // ================= PV phase: acc += P x MemGT ======================
        if (kt + 1 < nkt) STAGE_XMQ(0, kt + 1, 0);   // prefetch next k-tile chunk0
#pragma unroll
        for (int kc = 0; kc < 2; kc++) {
            bf16x8 A[4], B[8];
#pragma unroll
            for (int qt = 0; qt < 4; qt++)
                A[qt] = *(const bf16x8*)&lds[65536 + (qt * 16 + l15) * 128 +
                                             ((((kc << 2) + g) ^ (l15 & 7)) << 4)];
            const unsigned short* gb = GTZ + (size_t)(w * 128 + l15) * 1024 +
                                       kt * 64 + kc * 32 + g * 8;
#pragma unroll
            for (int dt = 0; dt < 8; dt++)
                B[dt] = *(const bf16x8*)(gb + (size_t)dt * 16 * 1024);
            __builtin_amdgcn_s_setprio(1);
#pragma unroll
            for (int qt = 0; qt < 4; qt++)
#pragma unroll
                for (int dt = 0; dt < 8; dt++)
                    acc[qt][dt] = __builtin_amdgcn_mfma_f32_16x16x32_bf16(
                        A[qt], B[dt], acc[qt][dt], 0, 0, 0);
            __builtin_amdgcn_s_setprio(0);
        }
        __builtin_amdgcn_s_barrier();   // P safe to overwrite next k-tile
    }
#undef GLL
#undef STAGE_XMQ

    // ================= epilogue: rowsum exchange + normalize + store =======
    rsum += __shfl_xor(rsum, 16, 64);
    rsum += __shfl_xor(rsum, 32, 64);
    if (lane < 16) *(float*)&lds[73728 + (w * 16 + l15) * 4] = rsum;
    __syncthreads();

#pragma unroll
    for (int qt = 0; qt < 4; qt++) {
        const f32x4 rsv = *(const f32x4*)&lds[73728 + (qt * 16 + g * 4) * 4];
        float ir[4];
#pragma unroll
        for (int r = 0; r < 4; r++) ir[r] = 1.0f / rsv[r];
#pragma unroll
        for (int dt = 0; dt < 8; dt++) {
            const int d = w * 128 + dt * 16 + l15;
#pragma unroll
            for (int r = 0; r < 4; r++) {
                const int q = qt * 16 + g * 4 + r;
                outZ[(size_t)q * 1024 + d] = acc[qt][dt][r] * ir[r];
            }
        }
    }
}

extern "C" void kernel_launch(void* const* d_in, const int* in_sizes, int n_in,
                              void* d_out, int out_size, void* d_ws, size_t ws_size,
                              hipStream_t stream)
{
    const float* inputs = (const float*)d_in[0];   // [32,1024,512]
    const float* memory = (const float*)d_in[1];   // [32,1024,512]
    const int*   mmask  = (const int*)d_in[2];     // [32,1024]
    const float* W_in   = (const float*)d_in[3];   // [512,512]
    const float* W_mem  = (const float*)d_in[4];   // [512,512]
    float* out = (float*)d_out;                    // [32,1024,1024]

    char* ws = (char*)d_ws;
    const unsigned long long MB = 1048576ull;
    unsigned short* Wt_in  = (unsigned short*)(ws);                   // 512 KiB
    unsigned short* Wt_mem = (unsigned short*)(ws + 524288);          // 512 KiB
    unsigned short* InB16  = (unsigned short*)(ws + 1 * MB);          // 32 MiB
    unsigned short* MemG   = (unsigned short*)(ws + 33 * MB);         // 32 MiB
    unsigned short* MemGT  = (unsigned short*)(ws + 65 * MB);         // 32 MiB
    unsigned short* Xq     = (unsigned short*)(ws + 97 * MB);         // 32 MiB
    unsigned short* Xm     = (unsigned short*)(ws + 129 * MB);        // 32 MiB
    int*            cntp   = (int*)(ws + 161 * MB + 262144);          // 128 B
    int*            padp   = (int*)(ws + 161 * MB + 262144 + 128);    // 128 B

    const float scale = 0.04419417382415922f;  // 1/sqrt(512)

    // 1. everything independent in one dispatch
    prep_kernel<<<17952, 256, 0, stream>>>(
        (const float4*)inputs, (uint2*)InB16, (float4*)out,
        W_in, W_mem, Wt_in, Wt_mem,
        mmask, cntp, padp,
        memory, MemG, MemGT);

    // 2. both projections (2 blocks/CU)
    gemm_proj_kernel<<<2048, 256, 0, stream>>>(
        InB16, Wt_in, Xq, MemG, Wt_mem, Xm, padp);

    // 3. fused softmax-attention: context -> out[..., 0:512]
    fused_attn_kernel<<<512, 256, 0, stream>>>(
        Xq, Xm, MemGT, out, cntp, padp, scale);
}